// Round 2
// baseline (163.607 us; speedup 1.0000x reference)
//
#include <hip/hip_runtime.h>

// out[b,o,n] = sum_{i,k} x[b,i,4n+k] * w[o,i,4n+k] / sqrt(128)
// x: (64,128,4096) f32, w: (128,128,4096) f32, out: (64,128,1024) f32.
//
// Round-2 structure: grid 512 = 256 n-groups (NB=4 n each) x 2 o-halves.
// Each block: full 64 b x 64 o tile for its 4 n. The two o-halves of one
// n-group land on the same XCD (swizzle) -> shared x-slice hits L2, so HBM
// fetch stays ~1x. 512 threads, LDS 72 KB -> 2 blocks/CU.
// Pipeline: double-buffered LDS, raw s_barrier + explicit lgkmcnt (NO
// __syncthreads vmcnt(0) drain), depth-1 register prefetch of the next
// chunk's global loads so they stay in flight across the barrier.

#define CIN    128
#define COUT   128
#define ODIM   1024
#define DDIM   4096
#define NB     4
#define CI     8            // cin per chunk -> K = 32
#define NCHUNK (CIN/CI)     // 16
#define LROW   36           // 32 data shorts + 4 pad (18 words, spreads banks)
#define XPL    (64*LROW + 2)  // n-plane stride in shorts (+1 word pad)
#define BUFS   (NB*XPL)       // shorts per buffer (9224)

typedef short  bf16x8 __attribute__((ext_vector_type(8)));
typedef short  s16x4  __attribute__((ext_vector_type(4)));
typedef float  f32x4  __attribute__((ext_vector_type(4)));

static __device__ __forceinline__ unsigned short f2bf(float f) {
    unsigned int u = __float_as_uint(f);
    u += 0x7fffu + ((u >> 16) & 1u);   // RNE fp32 -> bf16
    return (unsigned short)(u >> 16);
}
static __device__ __forceinline__ s16x4 cvt4(float4 v) {
    s16x4 s;
    s[0] = (short)f2bf(v.x); s[1] = (short)f2bf(v.y);
    s[2] = (short)f2bf(v.z); s[3] = (short)f2bf(v.w);
    return s;
}

__global__ __launch_bounds__(512, 4)
void nolc_kernel(const float* __restrict__ xg,
                 const float* __restrict__ wg,
                 float* __restrict__ outg) {
    __shared__ short xs[2 * BUFS];   // 36896 B
    __shared__ short ws[2 * BUFS];   // 36896 B

    const int bid  = blockIdx.x;
    const int xcd  = bid & 7;
    const int gidx = xcd * 64 + (bid >> 3);   // XCD-contiguous
    const int bn   = gidx >> 1;               // 0..255
    const int oh   = gidx & 1;                // o-half

    const int t    = threadIdx.x;
    const int lane = t & 63;
    const int wave = t >> 6;                  // 0..7
    const int dbase = 16 * bn;

    // ---- staging decomposition (it in 0..3 advances the row by +16) ----
    const int sn  = t & 3;          // which n (16B sub-segment of the 64B row)
    const int sii = (t >> 2) & 7;   // cin within chunk
    const int sr  = t >> 5;         // row 0..15
    const size_t ITS  = (size_t)16 * CIN * DDIM;  // +16 rows (b or o)
    const size_t CSTR = (size_t)CI * DDIM;        // next cin-chunk

    const float* xp = xg + (size_t)(sr * CIN + sii) * DDIM + dbase + 4 * sn;
    const float* wp = wg + ((size_t)(oh * 64 + sr) * CIN + sii) * DDIM + dbase + 4 * sn;
    const int ldso = sn * XPL + sr * LROW + sii * 4;   // shorts; it: +16*LROW

    // ---- compute decomposition ----
    const int bt  = wave & 3;       // 16-row b tile
    const int ot  = wave >> 2;      // 32-col o tile (0..1)
    const int row = lane & 15;
    const int kg  = lane >> 4;

    f32x4 acc[2][4];
#pragma unroll
    for (int j = 0; j < 2; ++j)
#pragma unroll
        for (int n = 0; n < 4; ++n)
            acc[j][n] = (f32x4){0.f, 0.f, 0.f, 0.f};

    float4 rxA[4], rwA[4], rxB[4], rwB[4];

#define LOADC(rx, rw, c)                                                     \
    do {                                                                     \
        const float* _xp = xp + (size_t)(c) * CSTR;                          \
        const float* _wp = wp + (size_t)(c) * CSTR;                          \
        _Pragma("unroll")                                                    \
        for (int it = 0; it < 4; ++it) {                                     \
            rx[it] = *reinterpret_cast<const float4*>(_xp + it * ITS);       \
            rw[it] = *reinterpret_cast<const float4*>(_wp + it * ITS);       \
        }                                                                    \
    } while (0)

#define STAGE(rx, rw, sel)                                                   \
    do {                                                                     \
        _Pragma("unroll")                                                    \
        for (int it = 0; it < 4; ++it) {                                     \
            *reinterpret_cast<s16x4*>(&xs[(sel) * BUFS + ldso + it * 16 * LROW]) = cvt4(rx[it]); \
            *reinterpret_cast<s16x4*>(&ws[(sel) * BUFS + ldso + it * 16 * LROW]) = cvt4(rw[it]); \
        }                                                                    \
    } while (0)

#define COMPUTE(sel)                                                         \
    do {                                                                     \
        const short* _xb = &xs[(sel) * BUFS + (bt * 16 + row) * LROW + kg * 8]; \
        const short* _wb = &ws[(sel) * BUFS + (ot * 32 + row) * LROW + kg * 8]; \
        _Pragma("unroll")                                                    \
        for (int n = 0; n < 4; ++n) {                                        \
            bf16x8 a = *reinterpret_cast<const bf16x8*>(_xb + n * XPL);      \
            _Pragma("unroll")                                                \
            for (int j = 0; j < 2; ++j) {                                    \
                bf16x8 bb = *reinterpret_cast<const bf16x8*>(_wb + n * XPL + j * 16 * LROW); \
                acc[j][n] = __builtin_amdgcn_mfma_f32_16x16x32_bf16(a, bb, acc[j][n], 0, 0, 0); \
            }                                                                \
        }                                                                    \
    } while (0)

    LOADC(rxA, rwA, 0);
    for (int c = 0; c < NCHUNK; c += 2) {
        // chunk c -> buffer 0
        LOADC(rxB, rwB, c + 1);              // prefetch next (stays in flight)
        STAGE(rxA, rwA, 0);                  // counted vmcnt waits only on A
        asm volatile("s_waitcnt lgkmcnt(0)" ::: "memory");
        __builtin_amdgcn_s_barrier();        // no vmcnt drain here
        COMPUTE(0);

        // chunk c+1 -> buffer 1
        if (c + 2 < NCHUNK) LOADC(rxA, rwA, c + 2);
        STAGE(rxB, rwB, 1);
        asm volatile("s_waitcnt lgkmcnt(0)" ::: "memory");
        __builtin_amdgcn_s_barrier();
        COMPUTE(1);
    }
#undef LOADC
#undef STAGE
#undef COMPUTE

    // ---- epilogue: out[b, o, 4*bn + n] ----
    const float scale = 0.08838834764831845f;  // 1/sqrt(128)
#pragma unroll
    for (int j = 0; j < 2; ++j) {
        const int o = oh * 64 + ot * 32 + j * 16 + row;
#pragma unroll
        for (int r = 0; r < 4; ++r) {
            const int b = bt * 16 + kg * 4 + r;
            float4 v;
            v.x = acc[j][0][r] * scale;
            v.y = acc[j][1][r] * scale;
            v.z = acc[j][2][r] * scale;
            v.w = acc[j][3][r] * scale;
            *reinterpret_cast<float4*>(outg + ((size_t)b * COUT + o) * ODIM + 4 * bn) = v;
        }
    }
}

extern "C" void kernel_launch(void* const* d_in, const int* in_sizes, int n_in,
                              void* d_out, int out_size, void* d_ws, size_t ws_size,
                              hipStream_t stream) {
    const float* x = (const float*)d_in[0];
    const float* w = (const float*)d_in[1];
    float* out = (float*)d_out;
    nolc_kernel<<<dim3(512), dim3(512), 0, stream>>>(x, w, out);
}

// Round 3
// 132.785 us; speedup vs baseline: 1.2321x; 1.2321x over previous
//
#include <hip/hip_runtime.h>

// out[b,o,n] = sum_{i,k} x[b,i,4n+k] * w[o,i,4n+k] / sqrt(128)
// x: (64,128,4096) f32, w: (128,128,4096) f32, out: (64,128,1024) f32.
//
// Round-3: widen DRAM granule 64B -> 128B. NB=8 n per block (d-span 128 B),
// grid 256 = 128 bn-groups x 2 o-halves (o-half pair adjacent -> same XCD,
// x dedups in L2). 1024 threads, full 64b x 64o tile, LDS 128 KB exactly
// (2 x 32 KB x-buf + 2 x 32 KB w-buf, double-buffered).
// LDS layout per row (b or o): [n 8][ii 8][k 4] bf16 = 512 B, XOR-swizzled in
// 16 B pieces (piece ^= row&7) -> conflict-free-ish ds_write_b64 / ds_read_b128.
// Pipeline: depth-1 register prefetch + single s_barrier per chunk (counted
// vmcnt keeps next chunk's 8 loads in flight across the barrier).

#define CIN    128
#define COUT   128
#define ODIM   1024
#define DDIM   4096
#define NB     8            // n per block
#define CI     8            // cin per chunk -> K = 32
#define NCH    16           // 128 / CI
#define RS     256          // shorts per LDS row (8n * 8ii * 4k)

typedef short  bf16x8 __attribute__((ext_vector_type(8)));
typedef short  s16x4  __attribute__((ext_vector_type(4)));
typedef float  f32x4  __attribute__((ext_vector_type(4)));

static __device__ __forceinline__ unsigned short f2bf(float f) {
    unsigned int u = __float_as_uint(f);
    u += 0x7fffu + ((u >> 16) & 1u);   // RNE fp32 -> bf16
    return (unsigned short)(u >> 16);
}
static __device__ __forceinline__ s16x4 cvt4(float4 v) {
    s16x4 s;
    s[0] = (short)f2bf(v.x); s[1] = (short)f2bf(v.y);
    s[2] = (short)f2bf(v.z); s[3] = (short)f2bf(v.w);
    return s;
}

__global__ __launch_bounds__(1024, 4)
void nolc_kernel(const float* __restrict__ xg,
                 const float* __restrict__ wg,
                 float* __restrict__ outg) {
    __shared__ short xs[2][64 * RS];   // 2 x 32 KB
    __shared__ short ws[2][64 * RS];   // 2 x 32 KB   -> 128 KB total

    const int bid  = blockIdx.x;
    const int gidx = (bid & 7) * 32 + (bid >> 3);  // XCD-contiguous
    const int bng  = gidx >> 1;        // 0..127  (8 n each)
    const int oh   = gidx & 1;         // o-half

    const int t    = threadIdx.x;
    const int lane = t & 63;
    const int wave = t >> 6;           // 0..15
    const int bq   = wave & 3;         // b 16-row tile
    const int oq   = wave >> 2;        // o 16-col tile
    const int row  = lane & 15;
    const int kg   = lane >> 4;

    const int dbase = 32 * bng;        // float offset into D (128 B span)

    // ---- staging decomposition: fid = it*1024 + t, it in 0..3 (+16 rows) ----
    const int sn4  = t & 7;            // n (16 B piece of the 128 B span)
    const int sii  = (t >> 3) & 7;     // cin within chunk
    const int srow = t >> 6;           // row 0..15
    const size_t ITS  = (size_t)16 * CIN * DDIM;   // +16 rows
    const size_t CSTR = (size_t)CI * DDIM;         // next cin-chunk

    const float* xp = xg + (size_t)(srow * CIN + sii) * DDIM + dbase + 4 * sn4;
    const float* wp = wg + ((size_t)(oh * 64 + srow) * CIN + sii) * DDIM + dbase + 4 * sn4;

    // LDS write offset (shorts): row*RS + ((piece ^ (row&7))<<3) + (sii&1)*4
    // piece = sn4*4 + (sii>>1); (row+16*it)&7 == row&7 -> it-invariant swizzle
    const int spiece = sn4 * 4 + (sii >> 1);
    const int ldso = srow * RS + (((spiece ^ (srow & 7))) << 3) + (sii & 1) * 4;
    // it advances +16 rows = +16*RS shorts

    f32x4 acc[NB];
#pragma unroll
    for (int n = 0; n < NB; ++n) acc[n] = (f32x4){0.f, 0.f, 0.f, 0.f};

    float4 rxA[4], rwA[4], rxB[4], rwB[4];

#define LOADC(rx, rw, c)                                                      \
    do {                                                                      \
        const float* _xp = xp + (size_t)(c) * CSTR;                           \
        const float* _wp = wp + (size_t)(c) * CSTR;                           \
        _Pragma("unroll")                                                     \
        for (int it = 0; it < 4; ++it) {                                      \
            rx[it] = *reinterpret_cast<const float4*>(_xp + it * ITS);        \
            rw[it] = *reinterpret_cast<const float4*>(_wp + it * ITS);        \
        }                                                                     \
    } while (0)

#define STAGE(rx, rw, sel)                                                    \
    do {                                                                      \
        _Pragma("unroll")                                                     \
        for (int it = 0; it < 4; ++it) {                                      \
            *reinterpret_cast<s16x4*>(&xs[sel][ldso + it * 16 * RS]) = cvt4(rx[it]); \
            *reinterpret_cast<s16x4*>(&ws[sel][ldso + it * 16 * RS]) = cvt4(rw[it]); \
        }                                                                     \
    } while (0)

    // frag read: lrow*RS + ((n*4+kg) ^ (row&7))*8 ; lrow = q*16+row, swz uses row&7
    const int xrb = (bq * 16 + row) * RS;
    const int wrb = (oq * 16 + row) * RS;
    const int r8  = row & 7;

#define COMPUTE(sel)                                                          \
    do {                                                                      \
        _Pragma("unroll")                                                     \
        for (int n = 0; n < NB; ++n) {                                        \
            const int po = ((n * 4 + kg) ^ r8) * 8;                           \
            bf16x8 a  = *reinterpret_cast<const bf16x8*>(&xs[sel][xrb + po]); \
            bf16x8 bb = *reinterpret_cast<const bf16x8*>(&ws[sel][wrb + po]); \
            acc[n] = __builtin_amdgcn_mfma_f32_16x16x32_bf16(a, bb, acc[n], 0, 0, 0); \
        }                                                                     \
    } while (0)

    LOADC(rxA, rwA, 0);
    for (int c = 0; c < NCH; c += 2) {
        LOADC(rxB, rwB, c + 1);            // prefetch (stays in flight)
        STAGE(rxA, rwA, 0);                // counted vmcnt waits only on A
        asm volatile("s_waitcnt lgkmcnt(0)" ::: "memory");
        __builtin_amdgcn_s_barrier();
        COMPUTE(0);

        if (c + 2 < NCH) LOADC(rxA, rwA, c + 2);
        STAGE(rxB, rwB, 1);
        asm volatile("s_waitcnt lgkmcnt(0)" ::: "memory");
        __builtin_amdgcn_s_barrier();
        COMPUTE(1);
    }
#undef LOADC
#undef STAGE
#undef COMPUTE

    // ---- epilogue: lane holds o = oh*64+oq*16+row (col), b = bq*16+kg*4+r ----
    // out[b][o][8*bng + n]: 8 consecutive n per (b,o) -> two float4 stores
    const float scale = 0.08838834764831845f;  // 1/sqrt(128)
    const int o = oh * 64 + oq * 16 + row;
    const int n0 = 8 * bng;
#pragma unroll
    for (int r = 0; r < 4; ++r) {
        const int b = bq * 16 + kg * 4 + r;
        float* op = outg + ((size_t)b * COUT + o) * ODIM + n0;
        float4 v0, v1;
        v0.x = acc[0][r] * scale; v0.y = acc[1][r] * scale;
        v0.z = acc[2][r] * scale; v0.w = acc[3][r] * scale;
        v1.x = acc[4][r] * scale; v1.y = acc[5][r] * scale;
        v1.z = acc[6][r] * scale; v1.w = acc[7][r] * scale;
        *reinterpret_cast<float4*>(op)     = v0;
        *reinterpret_cast<float4*>(op + 4) = v1;
    }
}

extern "C" void kernel_launch(void* const* d_in, const int* in_sizes, int n_in,
                              void* d_out, int out_size, void* d_ws, size_t ws_size,
                              hipStream_t stream) {
    const float* x = (const float*)d_in[0];
    const float* w = (const float*)d_in[1];
    float* out = (float*)d_out;
    nolc_kernel<<<dim3(256), dim3(1024), 0, stream>>>(x, w, out);
}